// Round 5
// baseline (59.542 us; speedup 1.0000x reference)
//
#include <hip/hip_runtime.h>
#include <hip/hip_bf16.h>
#include <math.h>

#define NB   16
#define CIN  64
#define LEN  8192
#define LP2  8195     // rows: 0 = left pad(0), 1..8192 = x, 8193/8194 = right pad(0)
#define COUT 64
#define MSZ  192
#define TST  137      // tile stride (floats): 136 cols + 1 pad

typedef float  f32x4  __attribute__((ext_vector_type(4)));
typedef short  bf16x8 __attribute__((ext_vector_type(8)));

static __device__ inline unsigned short f2bf(float f) {
    __hip_bfloat16 h = __float2bfloat16(f);
    return *reinterpret_cast<unsigned short*>(&h);
}

// ---------------- Kernel F2: fused offset-conv + transpose-to-bf16 ----------------
// block: 128 l-positions. tile[c][col] covers gl = l0-4 .. l0+131.
__global__ __launch_bounds__(256) void fused2_kernel(
    const float* __restrict__ x, const float* __restrict__ w_off,
    const float* __restrict__ b_off, float* __restrict__ gbuf,
    unsigned int* __restrict__ xt32)
{
    __shared__ float tile[64 * TST];     // 35 KB
    __shared__ float ps[128][2][3];      // cross-wave conv partials, 3 KB

    int tid = threadIdx.x;
    int n  = blockIdx.x >> 6;
    int t  = blockIdx.x & 63;
    int l0 = t << 7;
    const float* xn = x + (size_t)n * (CIN * LEN);

    // stage x tile: float4 global loads, scalar LDS stores (odd stride)
    for (int j = tid; j < 64 * 34; j += 256) {
        int c = j / 34, f = j - c * 34;
        int gl0 = l0 - 4 + (f << 2);
        float4 v;
        if (gl0 >= 0 && gl0 <= LEN - 4) {
            v = *(const float4*)&xn[(size_t)c * LEN + gl0];
        } else {
            float* ve = (float*)&v;
            #pragma unroll
            for (int e = 0; e < 4; ++e) {
                int gl = gl0 + e;
                ve[e] = ((unsigned)gl < LEN) ? xn[(size_t)c * LEN + gl] : 0.f;
            }
        }
        float* ve = (float*)&v;
        int base = c * TST + (f << 2);
        tile[base + 0] = ve[0]; tile[base + 1] = ve[1];
        tile[base + 2] = ve[2]; tile[base + 3] = ve[3];
    }
    __syncthreads();

    // offset conv: wave wid = (lgrp, h); h = channel half (wave-uniform -> s_load weights)
    {
        int lane = tid & 63;
        int wid  = tid >> 6;
        int h    = wid & 1;
        int l_loc = ((wid >> 1) << 6) | lane;    // 0..127
        float a0 = 0.f, a1 = 0.f, a2 = 0.f;
        const float* wbase = w_off + (size_t)h * 96;   // (h*32 ch) * 3 taps
        #pragma unroll 8
        for (int ci = 0; ci < 32; ++ci) {
            int base = (((h << 5) | ci) * TST) + l_loc + 3;
            float xm = tile[base + 0];
            float x0 = tile[base + 1];
            float xp = tile[base + 2];
            const float* w0 = wbase + ci * 3;          // k=0 -> row 0
            const float* w1 = w0 + 384;                // k=1 -> row 2
            const float* w2 = w0 + 768;                // k=2 -> row 4
            a0 = fmaf(w0[0], xm, a0); a0 = fmaf(w0[1], x0, a0); a0 = fmaf(w0[2], xp, a0);
            a1 = fmaf(w1[0], xm, a1); a1 = fmaf(w1[1], x0, a1); a1 = fmaf(w1[2], xp, a1);
            a2 = fmaf(w2[0], xm, a2); a2 = fmaf(w2[1], x0, a2); a2 = fmaf(w2[2], xp, a2);
        }
        ps[l_loc][h][0] = a0; ps[l_loc][h][1] = a1; ps[l_loc][h][2] = a2;
        __syncthreads();
        if (h == 0) {
            int l = l0 + l_loc;
            float base = (float)(l + 1);
            float g0 = fminf(fmaxf(base + a0 + ps[l_loc][1][0] + b_off[0], 0.f), 8193.f);
            float g1 = fminf(fmaxf(base + a1 + ps[l_loc][1][1] + b_off[2], 0.f), 8193.f);
            float g2 = fminf(fmaxf(base + a2 + ps[l_loc][1][2] + b_off[4], 0.f), 8193.f);
            size_t gi = ((size_t)n * LEN + l) * 3;
            gbuf[gi + 0] = g0; gbuf[gi + 1] = g1; gbuf[gi + 2] = g2;
        }
    }

    // transpose to bf16: xt[row = 1+l][c], 2 bf16 per u32
    for (int j = tid; j < 128 * 32; j += 256) {
        int ll = j >> 5, cp = j & 31;
        float lo = tile[(cp << 1) * TST + ll + 4];
        float hi = tile[((cp << 1) | 1) * TST + ll + 4];
        unsigned int u = ((unsigned int)f2bf(hi) << 16) | f2bf(lo);
        xt32[((size_t)n * LP2 + 1 + l0 + ll) * 32 + cp] = u;
    }
    if (t == 0  && tid < 32) xt32[((size_t)n * LP2) * 32 + tid] = 0u;
    if (t == 63 && tid < 64) xt32[((size_t)n * LP2 + 8193 + (tid >> 5)) * 32 + (tid & 31)] = 0u;
}

// ---------------- Kernel W: pack w into MFMA B-fragment order (bf16) ----------------
__global__ __launch_bounds__(512) void wfrag_kernel(
    const float* __restrict__ w, unsigned short* __restrict__ wtf)
{
    int b = blockIdx.x;             // 24 blocks: b = ot*6 + ks
    int ot = b / 6, ks = b - ot * 6;
    int t = threadIdx.x;
    int l = t >> 3, s = t & 7;
    int o = ot * 16 + (l & 15);
    int m = ks * 32 + (l >> 4) * 8 + s;
    wtf[b * 512 + t] = f2bf(w[o * MSZ + m]);
}

// ---------------- Kernel D5: full-prefetch register-gather + bf16 MFMA ----------------
__global__ __launch_bounds__(256) void dconv5_kernel(
    const unsigned short* __restrict__ xt16, const unsigned short* __restrict__ wtf,
    const float* __restrict__ bias, const float* __restrict__ gbuf,
    float* __restrict__ out)
{
    __shared__ __align__(16) int2 meta[MSZ];
    int tid = threadIdx.x;

    // bijective XCD swizzle: XCD x = wg&7 serves n in {2x, 2x+1}
    int wg  = blockIdx.x;
    int xcd = wg & 7;
    int tt  = wg >> 3;
    int n   = (xcd << 1) | (tt >> 7);
    int p   = tt & 127;

    if (tid < MSZ) {
        int k = tid >> 6, r = tid & 63;
        int l = (r << 7) | p;
        float g  = gbuf[((size_t)n * LEN + l) * 3 + k];
        float fl = floorf(g);
        meta[tid] = make_int2((int)fl, __float_as_int(g - fl));
    }
    __syncthreads();

    int lane = tid & 63;
    int ct   = tid >> 6;
    int g4   = lane >> 4;
    unsigned int c = (unsigned int)(ct * 16 + (lane & 15));
    const unsigned short* xb = xt16 + (size_t)n * LP2 * 64;

    unsigned int xlA[8], xrA[8], xlB[8], xrB[8], xlC[8], xrC[8];
    unsigned int xlD[8], xrD[8], xlE[8], xrE[8], xlF[8], xrF[8];

    #define GATHER(KS, XL, XR) do {                                          \
        int mb = (KS) * 32 + g4 * 8;                                         \
        _Pragma("unroll")                                                    \
        for (int s = 0; s < 8; ++s) {                                        \
            unsigned int off = ((unsigned int)meta[mb + s].x << 6) + c;      \
            (XL)[s] = xb[off];                                               \
            (XR)[s] = xb[off + 64];                                          \
        }                                                                    \
    } while (0)

    // issue ALL 96 gather loads before any compute (vmcnt-deep pipeline)
    GATHER(0, xlA, xrA);
    GATHER(1, xlB, xrB);
    GATHER(2, xlC, xrC);
    GATHER(3, xlD, xrD);
    GATHER(4, xlE, xrE);
    GATHER(5, xlF, xrF);

    f32x4 acc[4] = {};

    #define STEP(KS, XL, XR) do {                                            \
        int mb = (KS) * 32 + g4 * 8;                                         \
        bf16x8 afrag;                                                        \
        _Pragma("unroll")                                                    \
        for (int s = 0; s < 8; ++s) {                                        \
            float a  = __int_as_float(meta[mb + s].y);                       \
            float vl = __uint_as_float((XL)[s] << 16);                       \
            float vr = __uint_as_float((XR)[s] << 16);                       \
            afrag[s] = (short)f2bf(fmaf(a, vr - vl, vl));                    \
        }                                                                    \
        _Pragma("unroll")                                                    \
        for (int ot = 0; ot < 4; ++ot) {                                     \
            bf16x8 bfrag = *(const bf16x8*)&wtf[(size_t)(((ot * 6 + (KS)) << 6) + lane) << 3]; \
            acc[ot] = __builtin_amdgcn_mfma_f32_16x16x32_bf16(afrag, bfrag, acc[ot], 0, 0, 0); \
        }                                                                    \
    } while (0)

    STEP(0, xlA, xrA);
    STEP(1, xlB, xrB);
    STEP(2, xlC, xrC);
    STEP(3, xlD, xrD);
    STEP(4, xlE, xrE);
    STEP(5, xlF, xrF);

    #undef GATHER
    #undef STEP

    int q0 = (p << 6) + ct * 16 + g4 * 4;
    #pragma unroll
    for (int ot = 0; ot < 4; ++ot) {
        int o = ot * 16 + (lane & 15);
        float bb = bias[o];
        float4 r4;
        r4.x = acc[ot][0] + bb;
        r4.y = acc[ot][1] + bb;
        r4.z = acc[ot][2] + bb;
        r4.w = acc[ot][3] + bb;
        *(float4*)&out[((size_t)n * COUT + o) * LEN + q0] = r4;
    }
}

extern "C" void kernel_launch(void* const* d_in, const int* in_sizes, int n_in,
                              void* d_out, int out_size, void* d_ws, size_t ws_size,
                              hipStream_t stream) {
    const float* x     = (const float*)d_in[0];
    const float* w_off = (const float*)d_in[1];
    const float* b_off = (const float*)d_in[2];
    const float* w     = (const float*)d_in[3];
    const float* b     = (const float*)d_in[4];
    float* out = (float*)d_out;

    const size_t GBUF_B = (size_t)NB * LEN * 3 * sizeof(float);     // 6,291,456
    const size_t WTF_B  = (size_t)MSZ * COUT * sizeof(short);       // 24,576
    float*          gbuf = (float*)d_ws;
    unsigned short* wtf  = (unsigned short*)((char*)d_ws + GBUF_B);
    unsigned int*   xt32 = (unsigned int*)((char*)d_ws + GBUF_B + WTF_B);
    unsigned short* xt16 = (unsigned short*)xt32;

    fused2_kernel<<<NB * (LEN / 128), 256, 0, stream>>>(x, w_off, b_off, gbuf, xt32);
    wfrag_kernel<<<24, 512, 0, stream>>>(w, wtf);
    dconv5_kernel<<<NB * 128, 256, 0, stream>>>(xt16, wtf, b, gbuf, out);
}

// Round 6
// 51.420 us; speedup vs baseline: 1.1580x; 1.1580x over previous
//
#include <hip/hip_runtime.h>
#include <hip/hip_bf16.h>
#include <math.h>

#define NB   16
#define CIN  64
#define LEN  8192
#define LP2  8195     // rows: 0 = left pad(0), 1..8192 = x, 8193/8194 = right pad(0)
#define COUT 64
#define MSZ  192

typedef float  f32x4  __attribute__((ext_vector_type(4)));
typedef short  bf16x8 __attribute__((ext_vector_type(8)));

static __device__ inline unsigned short f2bf(float f) {
    __hip_bfloat16 h = __float2bfloat16(f);
    return *reinterpret_cast<unsigned short*>(&h);
}

// ---------------- Kernel O3: offset conv, register weights, 8-wave channel split ----------------
__global__ __launch_bounds__(512) void offs3_kernel(
    const float* __restrict__ x, const float* __restrict__ w_off,
    const float* __restrict__ b_off, float* __restrict__ gbuf)
{
    __shared__ float ps[8][3][64];
    int tid  = threadIdx.x;
    int lane = tid & 63;
    int wid  = tid >> 6;              // 0..7 = channel block
    int n  = blockIdx.x >> 7;
    int t  = blockIdx.x & 127;
    int l0 = t << 6;
    int l  = l0 + lane;
    const float* xn = x + (size_t)n * (CIN * LEN);

    bool okm = (l >= 1);
    bool okp = (l < LEN - 1);

    float a0 = 0.f, a1 = 0.f, a2 = 0.f;
    #pragma unroll
    for (int ci = 0; ci < 8; ++ci) {
        int c = (wid << 3) | ci;
        const float* xc = xn + (size_t)c * LEN;
        float xm = okm ? xc[l - 1] : 0.f;
        float x0 = xc[l];
        float xp = okp ? xc[l + 1] : 0.f;
        const float* w0 = w_off + (size_t)c * 3;          // k=0 (row 0)
        const float* w1 = w0 + 384;                        // k=1 (row 2)
        const float* w2 = w0 + 768;                        // k=2 (row 4)
        a0 = fmaf(w0[0], xm, a0); a0 = fmaf(w0[1], x0, a0); a0 = fmaf(w0[2], xp, a0);
        a1 = fmaf(w1[0], xm, a1); a1 = fmaf(w1[1], x0, a1); a1 = fmaf(w1[2], xp, a1);
        a2 = fmaf(w2[0], xm, a2); a2 = fmaf(w2[1], x0, a2); a2 = fmaf(w2[2], xp, a2);
    }
    ps[wid][0][lane] = a0;
    ps[wid][1][lane] = a1;
    ps[wid][2][lane] = a2;
    __syncthreads();

    if (tid < 192) {
        int k = tid >> 6, ll = tid & 63;
        float s = b_off[2 * k];
        #pragma unroll
        for (int w8 = 0; w8 < 8; ++w8) s += ps[w8][k][ll];
        float g = fminf(fmaxf((float)(l0 + ll + 1) + s, 0.f), 8193.f);
        gbuf[((size_t)n * LEN + l0 + ll) * 3 + k] = g;
    }
}

// ---------------- Kernel X2: transpose x -> xt bf16 [row][c] ----------------
__global__ __launch_bounds__(256) void xtrans2_kernel(
    const float* __restrict__ x, unsigned int* __restrict__ xt32)
{
    __shared__ float tile[64 * 65];   // tile[l][c], stride 65
    int tid = threadIdx.x;
    int n  = blockIdx.x >> 7;
    int t  = blockIdx.x & 127;
    int l0 = t << 6;
    const float* xn = x + (size_t)n * (CIN * LEN);

    // phase 1: coalesced float4 reads along l; transposed LDS store
    for (int j = tid; j < 64 * 16; j += 256) {
        int c = j >> 4, f = j & 15;
        float4 v = *(const float4*)&xn[(size_t)c * LEN + l0 + (f << 2)];
        int base = ((f << 2)) * 65 + c;
        tile[base]       = v.x;
        tile[base + 65]  = v.y;
        tile[base + 130] = v.z;
        tile[base + 195] = v.w;
    }
    __syncthreads();

    // phase 2: write xt rows: each int4 = 8 channels packed bf16x2
    for (int j = tid; j < 64 * 8; j += 256) {
        int ll = j >> 3, g = j & 7;
        const float* r = &tile[ll * 65 + (g << 3)];
        uint4 u;
        u.x = ((unsigned int)f2bf(r[1]) << 16) | f2bf(r[0]);
        u.y = ((unsigned int)f2bf(r[3]) << 16) | f2bf(r[2]);
        u.z = ((unsigned int)f2bf(r[5]) << 16) | f2bf(r[4]);
        u.w = ((unsigned int)f2bf(r[7]) << 16) | f2bf(r[6]);
        *(uint4*)&xt32[((size_t)n * LP2 + 1 + l0 + ll) * 32 + (g << 2)] = u;
    }
    if (t == 0   && tid < 32) xt32[((size_t)n * LP2) * 32 + tid] = 0u;
    if (t == 127 && tid < 64) xt32[((size_t)n * LP2 + 8193 + (tid >> 5)) * 32 + (tid & 31)] = 0u;
}

// ---------------- Kernel W: pack w into MFMA B-fragment order (bf16) ----------------
__global__ __launch_bounds__(512) void wfrag_kernel(
    const float* __restrict__ w, unsigned short* __restrict__ wtf)
{
    int b = blockIdx.x;             // 24 blocks: b = ot*6 + ks
    int ot = b / 6, ks = b - ot * 6;
    int t = threadIdx.x;
    int l = t >> 3, s = t & 7;
    int o = ot * 16 + (l & 15);
    int m = ks * 32 + (l >> 4) * 8 + s;
    wtf[b * 512 + t] = f2bf(w[o * MSZ + m]);
}

// ---------------- Kernel D4 (round-4 best): 1-deep pipelined register-gather + bf16 MFMA ----------------
__global__ __launch_bounds__(256) void dconv4_kernel(
    const unsigned short* __restrict__ xt16, const unsigned short* __restrict__ wtf,
    const float* __restrict__ bias, const float* __restrict__ gbuf,
    float* __restrict__ out)
{
    __shared__ __align__(16) int2 meta[MSZ];
    int tid = threadIdx.x;

    // bijective XCD swizzle: XCD x = wg&7 serves only n in {2x, 2x+1}
    int wg  = blockIdx.x;
    int xcd = wg & 7;
    int tt  = wg >> 3;               // 0..255
    int n   = (xcd << 1) | (tt >> 7);
    int p   = tt & 127;

    if (tid < MSZ) {
        int k = tid >> 6, r = tid & 63;
        int l = (r << 7) | p;
        float g  = gbuf[((size_t)n * LEN + l) * 3 + k];
        float fl = floorf(g);
        meta[tid] = make_int2((int)fl, __float_as_int(g - fl));
    }
    __syncthreads();

    int lane = tid & 63;
    int ct   = tid >> 6;
    int g4   = lane >> 4;
    unsigned int c = (unsigned int)(ct * 16 + (lane & 15));
    const unsigned short* xb = xt16 + (size_t)n * LP2 * 64;

    f32x4 acc[4] = {};

    unsigned int xlA[8], xrA[8], xlB[8], xrB[8];
    float alA[8], alB[8];

    #define ISSUE(KS, XL, XR, AL) do {                                       \
        int mb = (KS) * 32 + g4 * 8;                                         \
        int2 mv[8];                                                          \
        _Pragma("unroll")                                                    \
        for (int q = 0; q < 4; ++q)                                          \
            *(int4*)&mv[q * 2] = *(const int4*)&meta[mb + q * 2];            \
        _Pragma("unroll")                                                    \
        for (int s = 0; s < 8; ++s) {                                        \
            unsigned int off = ((unsigned int)mv[s].x << 6) + c;             \
            (XL)[s] = xb[off];                                               \
            (XR)[s] = xb[off + 64];                                          \
            (AL)[s] = __int_as_float(mv[s].y);                               \
        }                                                                    \
    } while (0)

    #define STEP(KS, XL, XR, AL, NXL, NXR, NAL) do {                         \
        if ((KS) < 5) ISSUE((KS) + 1, NXL, NXR, NAL);                        \
        bf16x8 afrag;                                                        \
        _Pragma("unroll")                                                    \
        for (int s = 0; s < 8; ++s) {                                        \
            float a  = (AL)[s];                                              \
            float vl = __uint_as_float((XL)[s] << 16);                       \
            float vr = __uint_as_float((XR)[s] << 16);                       \
            afrag[s] = (short)f2bf(fmaf(a, vr - vl, vl));                    \
        }                                                                    \
        _Pragma("unroll")                                                    \
        for (int ot = 0; ot < 4; ++ot) {                                     \
            bf16x8 bfrag = *(const bf16x8*)&wtf[(size_t)(((ot * 6 + (KS)) << 6) + lane) << 3]; \
            acc[ot] = __builtin_amdgcn_mfma_f32_16x16x32_bf16(afrag, bfrag, acc[ot], 0, 0, 0); \
        }                                                                    \
    } while (0)

    ISSUE(0, xlA, xrA, alA);
    STEP(0, xlA, xrA, alA, xlB, xrB, alB);
    STEP(1, xlB, xrB, alB, xlA, xrA, alA);
    STEP(2, xlA, xrA, alA, xlB, xrB, alB);
    STEP(3, xlB, xrB, alB, xlA, xrA, alA);
    STEP(4, xlA, xrA, alA, xlB, xrB, alB);
    STEP(5, xlB, xrB, alB, xlA, xrA, alA);

    #undef ISSUE
    #undef STEP

    int q0 = (p << 6) + ct * 16 + g4 * 4;
    #pragma unroll
    for (int ot = 0; ot < 4; ++ot) {
        int o = ot * 16 + (lane & 15);
        float bb = bias[o];
        float4 r4;
        r4.x = acc[ot][0] + bb;
        r4.y = acc[ot][1] + bb;
        r4.z = acc[ot][2] + bb;
        r4.w = acc[ot][3] + bb;
        *(float4*)&out[((size_t)n * COUT + o) * LEN + q0] = r4;
    }
}

extern "C" void kernel_launch(void* const* d_in, const int* in_sizes, int n_in,
                              void* d_out, int out_size, void* d_ws, size_t ws_size,
                              hipStream_t stream) {
    const float* x     = (const float*)d_in[0];
    const float* w_off = (const float*)d_in[1];
    const float* b_off = (const float*)d_in[2];
    const float* w     = (const float*)d_in[3];
    const float* b     = (const float*)d_in[4];
    float* out = (float*)d_out;

    const size_t GBUF_B = (size_t)NB * LEN * 3 * sizeof(float);     // 6,291,456
    const size_t WTF_B  = (size_t)MSZ * COUT * sizeof(short);       // 24,576
    float*          gbuf = (float*)d_ws;
    unsigned short* wtf  = (unsigned short*)((char*)d_ws + GBUF_B);
    unsigned int*   xt32 = (unsigned int*)((char*)d_ws + GBUF_B + WTF_B);
    unsigned short* xt16 = (unsigned short*)xt32;

    offs3_kernel<<<NB * 128, 512, 0, stream>>>(x, w_off, b_off, gbuf);
    xtrans2_kernel<<<NB * 128, 256, 0, stream>>>(x, xt32);
    wfrag_kernel<<<24, 512, 0, stream>>>(w, wtf);
    dconv4_kernel<<<NB * 128, 256, 0, stream>>>(xt16, wtf, b, gbuf, out);
}

// Round 7
// 41.891 us; speedup vs baseline: 1.4214x; 1.2275x over previous
//
#include <hip/hip_runtime.h>
#include <hip/hip_bf16.h>
#include <math.h>

#define NB   16
#define CIN  64
#define LEN  8192
#define LP2  8195     // rows: 0 = left pad(0), 1..8192 = x, 8193/8194 = right pad(0)
#define COUT 64
#define MSZ  192

typedef float  f32x4  __attribute__((ext_vector_type(4)));
typedef short  bf16x8 __attribute__((ext_vector_type(8)));

static __device__ inline unsigned short f2bf(float f) {
    __hip_bfloat16 h = __float2bfloat16(f);
    return *reinterpret_cast<unsigned short*>(&h);
}

// ---------------- Kernel P: fused offset-conv + bf16 transpose + wfrag ----------------
// blocks 0..2047: (n,t) tile = 64 l-positions x 64 channels.
//   wave w owns channels 16w..16w+15; conv accumulated in registers with
//   s_load weights; x0 values re-used for the bf16 transpose (x read ONCE).
// blocks 2048..2071: pack w into MFMA B-fragment order.
__global__ __launch_bounds__(256) void prep_kernel(
    const float* __restrict__ x, const float* __restrict__ w_off,
    const float* __restrict__ b_off, const float* __restrict__ w,
    float* __restrict__ gbuf, unsigned int* __restrict__ xt32,
    unsigned short* __restrict__ wtf)
{
    int bid = blockIdx.x;
    int tid = threadIdx.x;

    if (bid >= NB * 128) {
        // ---- wfrag part: b = ot*6 + ks ----
        int b = bid - NB * 128;          // 0..23
        int ot = b / 6, ks = b - ot * 6;
        #pragma unroll
        for (int h = 0; h < 2; ++h) {
            int t2 = tid + h * 256;
            int lq = t2 >> 3, s = t2 & 7;
            int o = ot * 16 + (lq & 15);
            int m = ks * 32 + (lq >> 4) * 8 + s;
            wtf[b * 512 + t2] = f2bf(w[o * MSZ + m]);
        }
        return;
    }

    __shared__ float ps[4][3][64];          // conv partials per wave
    __shared__ unsigned int bt[64 * 33];    // transposed bf16x2, stride 33 (conflict-free)

    int lane = tid & 63;
    int wid  = __builtin_amdgcn_readfirstlane(tid >> 6);   // wave-uniform in SGPR
    int n  = bid >> 7;
    int t  = bid & 127;
    int l0 = t << 6;
    int l  = l0 + lane;
    const float* xn = x + (size_t)n * (CIN * LEN);
    bool okm = (l >= 1);
    bool okp = (l < LEN - 1);

    float a0 = 0.f, a1 = 0.f, a2 = 0.f;
    unsigned int pk[8];

    #pragma unroll
    for (int ci = 0; ci < 16; ci += 2) {
        int c0 = (wid << 4) | ci;
        const float* xc0 = xn + (size_t)c0 * LEN;
        const float* xc1 = xc0 + LEN;
        float xm0 = okm ? xc0[l - 1] : 0.f;
        float x00 = xc0[l];
        float xp0 = okp ? xc0[l + 1] : 0.f;
        float xm1 = okm ? xc1[l - 1] : 0.f;
        float x01 = xc1[l];
        float xp1 = okp ? xc1[l + 1] : 0.f;
        // weights: wave-uniform addresses -> scalar loads
        const float* wa = w_off + (size_t)c0 * 3;     // k=0 (out-ch 0)
        const float* wb = wa + 384;                   // k=1 (out-ch 2)
        const float* wc = wa + 768;                   // k=2 (out-ch 4)
        a0 = fmaf(wa[0], xm0, a0); a0 = fmaf(wa[1], x00, a0); a0 = fmaf(wa[2], xp0, a0);
        a0 = fmaf(wa[3], xm1, a0); a0 = fmaf(wa[4], x01, a0); a0 = fmaf(wa[5], xp1, a0);
        a1 = fmaf(wb[0], xm0, a1); a1 = fmaf(wb[1], x00, a1); a1 = fmaf(wb[2], xp0, a1);
        a1 = fmaf(wb[3], xm1, a1); a1 = fmaf(wb[4], x01, a1); a1 = fmaf(wb[5], xp1, a1);
        a2 = fmaf(wc[0], xm0, a2); a2 = fmaf(wc[1], x00, a2); a2 = fmaf(wc[2], xp0, a2);
        a2 = fmaf(wc[3], xm1, a2); a2 = fmaf(wc[4], x01, a2); a2 = fmaf(wc[5], xp1, a2);
        pk[ci >> 1] = ((unsigned int)f2bf(x01) << 16) | f2bf(x00);
    }

    ps[wid][0][lane] = a0;
    ps[wid][1][lane] = a1;
    ps[wid][2][lane] = a2;
    #pragma unroll
    for (int j = 0; j < 8; ++j)
        bt[lane * 33 + (wid << 3) + j] = pk[j];
    __syncthreads();

    // gbuf: 192 threads, k = tid>>6, ll = tid&63
    if (tid < 192) {
        int k = tid >> 6, ll = tid & 63;
        float s = b_off[2 * k];
        #pragma unroll
        for (int w4 = 0; w4 < 4; ++w4) s += ps[w4][k][ll];
        float g = fminf(fmaxf((float)(l0 + ll + 1) + s, 0.f), 8193.f);
        gbuf[((size_t)n * LEN + l0 + ll) * 3 + k] = g;
    }

    // xt write: thread -> (row = tid>>2, grp = tid&3), 8 u32 each, fully coalesced
    {
        int row = tid >> 2, grp = tid & 3;
        const unsigned int* src = &bt[row * 33 + (grp << 3)];
        uint4 u0, u1;
        u0.x = src[0]; u0.y = src[1]; u0.z = src[2]; u0.w = src[3];
        u1.x = src[4]; u1.y = src[5]; u1.z = src[6]; u1.w = src[7];
        size_t base = ((size_t)n * LP2 + 1 + l0 + row) * 32 + (grp << 3);
        *(uint4*)&xt32[base]     = u0;
        *(uint4*)&xt32[base + 4] = u1;
    }
    if (t == 0   && tid < 32) xt32[((size_t)n * LP2) * 32 + tid] = 0u;
    if (t == 127 && tid < 64) xt32[((size_t)n * LP2 + 8193 + (tid >> 5)) * 32 + (tid & 31)] = 0u;
}

// ---------------- Kernel D4 (frozen, round-4 best): 1-deep pipelined gather + bf16 MFMA ----------------
__global__ __launch_bounds__(256) void dconv4_kernel(
    const unsigned short* __restrict__ xt16, const unsigned short* __restrict__ wtf,
    const float* __restrict__ bias, const float* __restrict__ gbuf,
    float* __restrict__ out)
{
    __shared__ __align__(16) int2 meta[MSZ];
    int tid = threadIdx.x;

    // bijective XCD swizzle: XCD x = wg&7 serves only n in {2x, 2x+1}
    int wg  = blockIdx.x;
    int xcd = wg & 7;
    int tt  = wg >> 3;               // 0..255
    int n   = (xcd << 1) | (tt >> 7);
    int p   = tt & 127;

    if (tid < MSZ) {
        int k = tid >> 6, r = tid & 63;
        int l = (r << 7) | p;
        float g  = gbuf[((size_t)n * LEN + l) * 3 + k];
        float fl = floorf(g);
        meta[tid] = make_int2((int)fl, __float_as_int(g - fl));
    }
    __syncthreads();

    int lane = tid & 63;
    int ct   = tid >> 6;
    int g4   = lane >> 4;
    unsigned int c = (unsigned int)(ct * 16 + (lane & 15));
    const unsigned short* xb = xt16 + (size_t)n * LP2 * 64;

    f32x4 acc[4] = {};

    unsigned int xlA[8], xrA[8], xlB[8], xrB[8];
    float alA[8], alB[8];

    #define ISSUE(KS, XL, XR, AL) do {                                       \
        int mb = (KS) * 32 + g4 * 8;                                         \
        int2 mv[8];                                                          \
        _Pragma("unroll")                                                    \
        for (int q = 0; q < 4; ++q)                                          \
            *(int4*)&mv[q * 2] = *(const int4*)&meta[mb + q * 2];            \
        _Pragma("unroll")                                                    \
        for (int s = 0; s < 8; ++s) {                                        \
            unsigned int off = ((unsigned int)mv[s].x << 6) + c;             \
            (XL)[s] = xb[off];                                               \
            (XR)[s] = xb[off + 64];                                          \
            (AL)[s] = __int_as_float(mv[s].y);                               \
        }                                                                    \
    } while (0)

    #define STEP(KS, XL, XR, AL, NXL, NXR, NAL) do {                         \
        if ((KS) < 5) ISSUE((KS) + 1, NXL, NXR, NAL);                        \
        bf16x8 afrag;                                                        \
        _Pragma("unroll")                                                    \
        for (int s = 0; s < 8; ++s) {                                        \
            float a  = (AL)[s];                                              \
            float vl = __uint_as_float((XL)[s] << 16);                       \
            float vr = __uint_as_float((XR)[s] << 16);                       \
            afrag[s] = (short)f2bf(fmaf(a, vr - vl, vl));                    \
        }                                                                    \
        _Pragma("unroll")                                                    \
        for (int ot = 0; ot < 4; ++ot) {                                     \
            bf16x8 bfrag = *(const bf16x8*)&wtf[(size_t)(((ot * 6 + (KS)) << 6) + lane) << 3]; \
            acc[ot] = __builtin_amdgcn_mfma_f32_16x16x32_bf16(afrag, bfrag, acc[ot], 0, 0, 0); \
        }                                                                    \
    } while (0)

    ISSUE(0, xlA, xrA, alA);
    STEP(0, xlA, xrA, alA, xlB, xrB, alB);
    STEP(1, xlB, xrB, alB, xlA, xrA, alA);
    STEP(2, xlA, xrA, alA, xlB, xrB, alB);
    STEP(3, xlB, xrB, alB, xlA, xrA, alA);
    STEP(4, xlA, xrA, alA, xlB, xrB, alB);
    STEP(5, xlB, xrB, alB, xlA, xrA, alA);

    #undef ISSUE
    #undef STEP

    int q0 = (p << 6) + ct * 16 + g4 * 4;
    #pragma unroll
    for (int ot = 0; ot < 4; ++ot) {
        int o = ot * 16 + (lane & 15);
        float bb = bias[o];
        float4 r4;
        r4.x = acc[ot][0] + bb;
        r4.y = acc[ot][1] + bb;
        r4.z = acc[ot][2] + bb;
        r4.w = acc[ot][3] + bb;
        *(float4*)&out[((size_t)n * COUT + o) * LEN + q0] = r4;
    }
}

extern "C" void kernel_launch(void* const* d_in, const int* in_sizes, int n_in,
                              void* d_out, int out_size, void* d_ws, size_t ws_size,
                              hipStream_t stream) {
    const float* x     = (const float*)d_in[0];
    const float* w_off = (const float*)d_in[1];
    const float* b_off = (const float*)d_in[2];
    const float* w     = (const float*)d_in[3];
    const float* b     = (const float*)d_in[4];
    float* out = (float*)d_out;

    const size_t GBUF_B = (size_t)NB * LEN * 3 * sizeof(float);     // 6,291,456
    const size_t WTF_B  = (size_t)MSZ * COUT * sizeof(short);       // 24,576
    float*          gbuf = (float*)d_ws;
    unsigned short* wtf  = (unsigned short*)((char*)d_ws + GBUF_B);
    unsigned int*   xt32 = (unsigned int*)((char*)d_ws + GBUF_B + WTF_B);
    unsigned short* xt16 = (unsigned short*)xt32;

    prep_kernel<<<NB * 128 + 24, 256, 0, stream>>>(x, w_off, b_off, w, gbuf, xt32, wtf);
    dconv4_kernel<<<NB * 128, 256, 0, stream>>>(xt16, wtf, b, gbuf, out);
}

// Round 8
// 37.437 us; speedup vs baseline: 1.5905x; 1.1190x over previous
//
#include <hip/hip_runtime.h>
#include <hip/hip_bf16.h>
#include <math.h>

#define NB   16
#define CIN  64
#define LEN  8192
#define LP2  8195     // rows: 0 = left pad(0), 1..8192 = x, 8193/8194 = right pad(0)
#define COUT 64
#define MSZ  192

typedef float  f32x4  __attribute__((ext_vector_type(4)));
typedef short  bf16x8 __attribute__((ext_vector_type(8)));

static __device__ inline unsigned short f2bf(float f) {
    __hip_bfloat16 h = __float2bfloat16(f);
    return *reinterpret_cast<unsigned short*>(&h);
}

// ---------------- Kernel P: fused offset-conv + bf16 transpose + wfrag (frozen) ----------------
__global__ __launch_bounds__(256) void prep_kernel(
    const float* __restrict__ x, const float* __restrict__ w_off,
    const float* __restrict__ b_off, const float* __restrict__ w,
    float* __restrict__ gbuf, unsigned int* __restrict__ xt32,
    unsigned short* __restrict__ wtf)
{
    int bid = blockIdx.x;
    int tid = threadIdx.x;

    if (bid >= NB * 128) {
        int b = bid - NB * 128;          // 0..23
        int ot = b / 6, ks = b - ot * 6;
        #pragma unroll
        for (int h = 0; h < 2; ++h) {
            int t2 = tid + h * 256;
            int lq = t2 >> 3, s = t2 & 7;
            int o = ot * 16 + (lq & 15);
            int m = ks * 32 + (lq >> 4) * 8 + s;
            wtf[b * 512 + t2] = f2bf(w[o * MSZ + m]);
        }
        return;
    }

    __shared__ float ps[4][3][64];
    __shared__ unsigned int bt[64 * 33];

    int lane = tid & 63;
    int wid  = __builtin_amdgcn_readfirstlane(tid >> 6);
    int n  = bid >> 7;
    int t  = bid & 127;
    int l0 = t << 6;
    int l  = l0 + lane;
    const float* xn = x + (size_t)n * (CIN * LEN);
    bool okm = (l >= 1);
    bool okp = (l < LEN - 1);

    float a0 = 0.f, a1 = 0.f, a2 = 0.f;
    unsigned int pk[8];

    #pragma unroll
    for (int ci = 0; ci < 16; ci += 2) {
        int c0 = (wid << 4) | ci;
        const float* xc0 = xn + (size_t)c0 * LEN;
        const float* xc1 = xc0 + LEN;
        float xm0 = okm ? xc0[l - 1] : 0.f;
        float x00 = xc0[l];
        float xp0 = okp ? xc0[l + 1] : 0.f;
        float xm1 = okm ? xc1[l - 1] : 0.f;
        float x01 = xc1[l];
        float xp1 = okp ? xc1[l + 1] : 0.f;
        const float* wa = w_off + (size_t)c0 * 3;
        const float* wb = wa + 384;
        const float* wc = wa + 768;
        a0 = fmaf(wa[0], xm0, a0); a0 = fmaf(wa[1], x00, a0); a0 = fmaf(wa[2], xp0, a0);
        a0 = fmaf(wa[3], xm1, a0); a0 = fmaf(wa[4], x01, a0); a0 = fmaf(wa[5], xp1, a0);
        a1 = fmaf(wb[0], xm0, a1); a1 = fmaf(wb[1], x00, a1); a1 = fmaf(wb[2], xp0, a1);
        a1 = fmaf(wb[3], xm1, a1); a1 = fmaf(wb[4], x01, a1); a1 = fmaf(wb[5], xp1, a1);
        a2 = fmaf(wc[0], xm0, a2); a2 = fmaf(wc[1], x00, a2); a2 = fmaf(wc[2], xp0, a2);
        a2 = fmaf(wc[3], xm1, a2); a2 = fmaf(wc[4], x01, a2); a2 = fmaf(wc[5], xp1, a2);
        pk[ci >> 1] = ((unsigned int)f2bf(x01) << 16) | f2bf(x00);
    }

    ps[wid][0][lane] = a0;
    ps[wid][1][lane] = a1;
    ps[wid][2][lane] = a2;
    #pragma unroll
    for (int j = 0; j < 8; ++j)
        bt[lane * 33 + (wid << 3) + j] = pk[j];
    __syncthreads();

    if (tid < 192) {
        int k = tid >> 6, ll = tid & 63;
        float s = b_off[2 * k];
        #pragma unroll
        for (int w4 = 0; w4 < 4; ++w4) s += ps[w4][k][ll];
        float g = fminf(fmaxf((float)(l0 + ll + 1) + s, 0.f), 8193.f);
        gbuf[((size_t)n * LEN + l0 + ll) * 3 + k] = g;
    }

    {
        int row = tid >> 2, grp = tid & 3;
        const unsigned int* src = &bt[row * 33 + (grp << 3)];
        uint4 u0, u1;
        u0.x = src[0]; u0.y = src[1]; u0.z = src[2]; u0.w = src[3];
        u1.x = src[4]; u1.y = src[5]; u1.z = src[6]; u1.w = src[7];
        size_t base = ((size_t)n * LP2 + 1 + l0 + row) * 32 + (grp << 3);
        *(uint4*)&xt32[base]     = u0;
        *(uint4*)&xt32[base + 4] = u1;
    }
    if (t == 0   && tid < 32) xt32[((size_t)n * LP2) * 32 + tid] = 0u;
    if (t == 127 && tid < 64) xt32[((size_t)n * LP2 + 8193 + (tid >> 5)) * 32 + (tid & 31)] = 0u;
}

// ---------------- Kernel D6: LDS-staged B-tile + bf16 MFMA ----------------
// Per block (n,p): stage lerped B[192 m][64 c] (bf16, XOR-swizzled) via
// row-granular coalesced loads, then 6 MFMA steps reading conflict-free
// LDS columns. 12 global uint4 loads/thread vs dconv4's 96 u16 gathers.
__global__ __launch_bounds__(256) void dconv6_kernel(
    const unsigned short* __restrict__ xt16, const unsigned short* __restrict__ wtf,
    const float* __restrict__ bias, const float* __restrict__ gbuf,
    float* __restrict__ out)
{
    __shared__ unsigned short Bl[MSZ * 64];    // 24 KB
    __shared__ __align__(16) int2 meta[MSZ];
    int tid = threadIdx.x;

    // bijective XCD swizzle: XCD x = wg&7 serves only n in {2x, 2x+1}
    int wg  = blockIdx.x;
    int xcd = wg & 7;
    int tt  = wg >> 3;               // 0..255
    int n   = (xcd << 1) | (tt >> 7);
    int p   = tt & 127;

    if (tid < MSZ) {
        int k = tid >> 6, r = tid & 63;
        int l = (r << 7) | p;
        float g  = gbuf[((size_t)n * LEN + l) * 3 + k];
        float fl = floorf(g);
        meta[tid] = make_int2((int)fl, __float_as_int(g - fl));
    }
    __syncthreads();

    const unsigned short* xb = xt16 + (size_t)n * LP2 * 64;

    // ---- stage B: task = (m, 8-channel chunk); lanes 0-7 cover one full row ----
    #pragma unroll
    for (int j = 0; j < 6; ++j) {
        int task = tid + (j << 8);       // 0..1535
        int m  = task >> 3;
        int ch = task & 7;
        int2 mv = meta[m];
        float a = __int_as_float(mv.y);
        const unsigned short* rl = xb + ((size_t)(unsigned)mv.x << 6) + (ch << 3);
        uint4 vl4 = *(const uint4*)rl;          // xl: 8 ch bf16
        uint4 vr4 = *(const uint4*)(rl + 64);   // xr: next row
        const unsigned int* vl = (const unsigned int*)&vl4;
        const unsigned int* vr = (const unsigned int*)&vr4;
        unsigned int ov[4];
        #pragma unroll
        for (int q = 0; q < 4; ++q) {
            float l0 = __uint_as_float(vl[q] << 16);
            float l1 = __uint_as_float(vl[q] & 0xffff0000u);
            float r0 = __uint_as_float(vr[q] << 16);
            float r1 = __uint_as_float(vr[q] & 0xffff0000u);
            float b0 = fmaf(a, r0 - l0, l0);
            float b1 = fmaf(a, r1 - l1, l1);
            ov[q] = ((unsigned int)f2bf(b1) << 16) | f2bf(b0);
        }
        // XOR swizzle on bits 4-5 of the ushort index (32B windows):
        int dst = (m << 6) + ((ch << 3) ^ (((m >> 3) & 3) << 4));
        *(uint4*)&Bl[dst] = *(const uint4*)ov;
    }
    __syncthreads();

    int lane = tid & 63;
    int ct   = tid >> 6;
    int g4   = lane >> 4;
    int c    = (ct << 4) | (lane & 15);

    f32x4 acc[4] = {};

    #pragma unroll
    for (int ks = 0; ks < 6; ++ks) {
        int mb = ks * 32 + (g4 << 3);
        int cx = c ^ ((((unsigned)(mb >> 3)) & 3) << 4);   // (mb+s)>>3 constant for s<8
        bf16x8 afrag;
        #pragma unroll
        for (int s = 0; s < 8; ++s)
            afrag[s] = (short)Bl[((mb + s) << 6) + cx];

        #pragma unroll
        for (int ot = 0; ot < 4; ++ot) {
            bf16x8 bfrag = *(const bf16x8*)&wtf[(size_t)(((ot * 6 + ks) << 6) + lane) << 3];
            acc[ot] = __builtin_amdgcn_mfma_f32_16x16x32_bf16(afrag, bfrag, acc[ot], 0, 0, 0);
        }
    }

    // D layout: col(o) = lane&15, row(c-block) = (lane>>4)*4 + reg
    int q0 = (p << 6) + ct * 16 + g4 * 4;
    #pragma unroll
    for (int ot = 0; ot < 4; ++ot) {
        int o = ot * 16 + (lane & 15);
        float bb = bias[o];
        float4 r4;
        r4.x = acc[ot][0] + bb;
        r4.y = acc[ot][1] + bb;
        r4.z = acc[ot][2] + bb;
        r4.w = acc[ot][3] + bb;
        *(float4*)&out[((size_t)n * COUT + o) * LEN + q0] = r4;
    }
}

extern "C" void kernel_launch(void* const* d_in, const int* in_sizes, int n_in,
                              void* d_out, int out_size, void* d_ws, size_t ws_size,
                              hipStream_t stream) {
    const float* x     = (const float*)d_in[0];
    const float* w_off = (const float*)d_in[1];
    const float* b_off = (const float*)d_in[2];
    const float* w     = (const float*)d_in[3];
    const float* b     = (const float*)d_in[4];
    float* out = (float*)d_out;

    const size_t GBUF_B = (size_t)NB * LEN * 3 * sizeof(float);     // 6,291,456
    const size_t WTF_B  = (size_t)MSZ * COUT * sizeof(short);       // 24,576
    float*          gbuf = (float*)d_ws;
    unsigned short* wtf  = (unsigned short*)((char*)d_ws + GBUF_B);
    unsigned int*   xt32 = (unsigned int*)((char*)d_ws + GBUF_B + WTF_B);
    unsigned short* xt16 = (unsigned short*)xt32;

    prep_kernel<<<NB * 128 + 24, 256, 0, stream>>>(x, w_off, b_off, w, gbuf, xt32, wtf);
    dconv6_kernel<<<NB * 128, 256, 0, stream>>>(xt16, wtf, b, gbuf, out);
}